// Round 14
// baseline (28.158 us; speedup 1.0000x reference)
//
#include <hip/hip_runtime.h>

// DependencyGenerator, R14: R13 structure at 2 blocks/CU.
// Block b = (row r = b>>2, quarter q = b&3). Each block fills a contiguous
// 256 KB quarter-row and exclusively owns scatter targets idx>>16==q.
// Phase order (R13's proven trick): ALL global reads first -> fill stores ->
// LDS-hash insert (pure LDS/VALU, overlaps store drain) -> barrier (drains
// own stores; targets block-exclusive) -> winners store.
// 512 blocks = 2/CU: partner block's fill covers this block's staging
// preamble and drain/scatter tail (at 256 blocks = 1/CU both were exposed).

#define SEQ_L   512
#define LM1     511
#define ROWELEM (SEQ_L * SEQ_L)      // 262144 floats per row
#define QUART   (ROWELEM / 4)        // 65536 floats (2^16)
#define NT      256
#define HSLOTS  512                  // ~128 keys -> load 0.25
#define NEMBMAX 64

typedef float vfloat4 __attribute__((ext_vector_type(4)));

__device__ __forceinline__ unsigned hash_key(unsigned key) {
    return (key * 2654435761u) >> 23;            // 9 bits
}

__global__ __launch_bounds__(NT) void depmask_fused(
    const int*   __restrict__ dep_i,
    const int*   __restrict__ dep_j,
    const int*   __restrict__ dep_type,
    const float* __restrict__ dep_emb,
    float*       __restrict__ out,
    int nemb)
{
    __shared__ int      h_key[HSLOTS];
    __shared__ unsigned h_pack[HSLOTS];
    __shared__ float    s_emb[NEMBMAX];

    const int b   = blockIdx.x;
    const int row = b >> 2;
    const int qtr = b & 3;
    const int t   = threadIdx.x;

    // Phase A: all global reads up front (nothing big outstanding yet).
    if (t < nemb) s_emb[t] = dep_emb[t];
    #pragma unroll
    for (int s = t; s < HSLOTS; s += NT) { h_key[s] = -1; h_pack[s] = 0; }

    const int base = row * LM1;
    const int k0 = t, k1 = t + NT;
    const int idx0 = dep_i[base + k0] * SEQ_L + dep_j[base + k0];
    const int ty0  = dep_type[base + k0];
    int idx1 = -1, ty1 = 0;
    if (k1 < LM1) {
        idx1 = dep_i[base + k1] * SEQ_L + dep_j[base + k1];
        ty1  = dep_type[base + k1];
    }

    // Phase B: hash init + staged loads complete (cheap barrier).
    __syncthreads();

    const float val0 = s_emb[ty0];
    const float val1 = (idx1 >= 0) ? s_emb[ty1] : 0.f;

    // Phase C: fill own quarter-row (contiguous 256 KB, 64 f4 stores/thr).
    {
        const vfloat4 ones = {1.f, 1.f, 1.f, 1.f};
        vfloat4* o4 = reinterpret_cast<vfloat4*>(out)
                    + (size_t)row * (ROWELEM / 4) + (size_t)qtr * (QUART / 4);
        #pragma unroll 4
        for (int it = 0; it < QUART / 4 / NT; ++it)     // 64 stores
            o4[it * NT + t] = ones;
    }

    // Phase D: hash-insert own-quarter entries (LDS/VALU only -> overlaps
    // the store drain; no vmem dependency).
    if ((idx0 >> 16) == qtr) {
        const unsigned key = (unsigned)idx0 & 0xFFFFu;
        const unsigned pack = ((unsigned)k0 << 16) | key;
        unsigned s = hash_key(key);
        while (true) {
            int prev = atomicCAS(&h_key[s], -1, (int)key);
            if (prev == -1 || prev == (int)key) { atomicMax(&h_pack[s], pack); break; }
            s = (s + 1) & (HSLOTS - 1);
        }
    }
    if (idx1 >= 0 && (idx1 >> 16) == qtr) {
        const unsigned key = (unsigned)idx1 & 0xFFFFu;
        const unsigned pack = ((unsigned)k1 << 16) | key;
        unsigned s = hash_key(key);
        while (true) {
            int prev = atomicCAS(&h_key[s], -1, (int)key);
            if (prev == -1 || prev == (int)key) { atomicMax(&h_pack[s], pack); break; }
            s = (s + 1) & (HSLOTS - 1);
        }
    }

    // Phase E: drains own fill stores; hash stable. Scatter targets below
    // are exclusively this block's (idx>>16==qtr) -> no cross-block order.
    __syncthreads();

    // Phase F: winner-check (pack equality = max k) -> scatter store.
    if ((idx0 >> 16) == qtr) {
        const unsigned key = (unsigned)idx0 & 0xFFFFu;
        const unsigned pack = ((unsigned)k0 << 16) | key;
        unsigned s = hash_key(key);
        while (h_key[s] != (int)key) s = (s + 1) & (HSLOTS - 1);
        if (h_pack[s] == pack) out[(size_t)row * ROWELEM + idx0] = val0;
    }
    if (idx1 >= 0 && (idx1 >> 16) == qtr) {
        const unsigned key = (unsigned)idx1 & 0xFFFFu;
        const unsigned pack = ((unsigned)k1 << 16) | key;
        unsigned s = hash_key(key);
        while (h_key[s] != (int)key) s = (s + 1) & (HSLOTS - 1);
        if (h_pack[s] == pack) out[(size_t)row * ROWELEM + idx1] = val1;
    }
}

extern "C" void kernel_launch(void* const* d_in, const int* in_sizes, int n_in,
                              void* d_out, int out_size, void* d_ws, size_t ws_size,
                              hipStream_t stream) {
    const int*   dep_i    = (const int*)  d_in[0];
    const int*   dep_j    = (const int*)  d_in[1];
    const int*   dep_type = (const int*)  d_in[2];
    // d_in[3] = seq_len scalar (512)
    const float* dep_emb  = (const float*)d_in[4];
    float*       out      = (float*)      d_out;

    const int rows = in_sizes[0] / LM1;          // 128
    const int nemb = in_sizes[4];                // 53

    depmask_fused<<<dim3(4 * rows), dim3(NT), 0, stream>>>(
        dep_i, dep_j, dep_type, dep_emb, out, nemb);
}